// Round 5
// baseline (306.806 us; speedup 1.0000x reference)
//
#include <hip/hip_runtime.h>
#include <math.h>

// Round 10: two-dispatch pipeline (launch overhead measured ~24us/dispatch:
// 5 dispatches -> 2 saves ~70us). prep_kernel fuses Wq/Wo transpose + kv GEMM
// (direct Wk/Wv reads, per-(b,h) LDS-transposed W slice) + kvp zero-fill.
// fused kernel: 512 threads / 8 waves (only config that ever exceeded 4
// waves/CU), acc[2][5] phases + launch_bounds(512,4) to cap VGPR at 128.

#define NUM_HEADS 8
#define DIM_HEAD 40
#define INNER 320
#define DQ 320
#define DC 768
#define SEQ_T 4096
#define SEQ_S 77
#define BATCH 16
#define SCALE 0.39763536438352531f

typedef __attribute__((ext_vector_type(8))) short short8;
typedef __attribute__((ext_vector_type(4))) float floatx4;

__device__ __forceinline__ unsigned short f2bf(float f) {
  unsigned u = __float_as_uint(f);
  u += 0x7FFFu + ((u >> 16) & 1u);   // RNE
  return (unsigned short)(u >> 16);
}

__device__ __forceinline__ short8 pack8(float4 a, float4 b) {
  short8 pk;
  pk[0] = (short)f2bf(a.x); pk[1] = (short)f2bf(a.y);
  pk[2] = (short)f2bf(a.z); pk[3] = (short)f2bf(a.w);
  pk[4] = (short)f2bf(b.x); pk[5] = (short)f2bf(b.y);
  pk[6] = (short)f2bf(b.z); pk[7] = (short)f2bf(b.w);
  return pk;
}

// qs swizzle: 16B-unit index for (row, unit-col). 40 units per 320-short row.
__device__ __forceinline__ int qsi(int row, int uc) {
  return (row * 40 + (uc ^ (row & 7))) * 8;
}

// ------------------------------------------------- prep kernel (one dispatch)
// bid 0..127   : kv role, (b = bid>>3, h = bid&7) -> kvp tile K[80][40]|Vt[48][104]
// bid 128..227 : Wq transpose tile (32x32), scaled by SCALE
// bid 228..327 : Wo transpose tile
__global__ __launch_bounds__(512) void prep_kernel(
    const float* __restrict__ ctx, const float* __restrict__ Wq,
    const float* __restrict__ Wk, const float* __restrict__ Wv,
    const float* __restrict__ Wo, unsigned short* __restrict__ WqT,
    unsigned short* __restrict__ WoT, unsigned short* __restrict__ kvp) {
  __shared__ __align__(16) char smem[11520];
  const int bid = blockIdx.x;
  const int tid = threadIdx.x;

  if (bid >= 128) {   // ---- transpose roles
    const int z = bid - 128;
    const float* W; unsigned short* WT; float scl;
    int zz;
    if (z < 100) { W = Wq; WT = WqT; scl = SCALE; zz = z; }
    else         { W = Wo; WT = WoT; scl = 1.0f;  zz = z - 100; }
    const int k0 = (zz % 10) * 32, n0 = (zz / 10) * 32;
    float* tile = (float*)smem;   // [32][33]
    const int tx = tid & 31, ty = tid >> 5;   // ty 0..15
    #pragma unroll
    for (int r = 0; r < 2; ++r)
      tile[(ty + r * 16) * 33 + tx] = W[(size_t)(k0 + ty + r * 16) * 320 + n0 + tx];
    __syncthreads();
    #pragma unroll
    for (int r = 0; r < 2; ++r)
      WT[(size_t)(n0 + ty + r * 16) * 320 + k0 + tx] =
          f2bf(tile[tx * 33 + ty + r * 16] * scl);
    return;
  }

  // ---- kv role: GEMM (ctx[b] @ [Wk|Wv] head-h slice) + pack + zero-fill
  const int b = bid >> 3, h = bid & 7;
  unsigned short* dst = kvp + (size_t)bid * 8192;
  // zero entire tile (pad rows/cols must be finite-zero); barrier below orders
  {
    int4 zv = make_int4(0, 0, 0, 0);
    #pragma unroll
    for (int i = 0; i < 2; ++i) ((int4*)dst)[tid + i * 512] = zv;
  }
  unsigned short* Ws = (unsigned short*)smem;   // [80][72] bf16 W^T slice
  const int lane = tid & 63, wave = tid >> 6;
  const int lrow = lane & 15, quad = lane >> 4;
  const short8 zero8 = {0, 0, 0, 0, 0, 0, 0, 0};

  floatx4 acc[5];
  #pragma unroll
  for (int j = 0; j < 5; ++j) acc[j] = (floatx4){0.f, 0.f, 0.f, 0.f};

  const int kk = tid >> 3, grp = tid & 7;
  for (int kt = 0; kt < 12; ++kt) {
    const int k0 = kt * 64;
    __syncthreads();   // prev Ws reads done (also orders the zero-fill)
    {  // stage W'^T[c][k] for this 64-k slab: c<40 = Wk*SCALE, 40..79 = Wv
      const float* wkrow = Wk + (size_t)(k0 + kk) * 320 + h * DIM_HEAD;
      const float* wvrow = Wv + (size_t)(k0 + kk) * 320 + h * DIM_HEAD;
      #pragma unroll
      for (int i = 0; i < 5; ++i) {
        int c = grp * 5 + i;
        Ws[c * 72 + kk]        = f2bf(wkrow[c] * SCALE);
        Ws[(40 + c) * 72 + kk] = f2bf(wvrow[c]);
      }
    }
    __syncthreads();
    if (wave < 5) {
      const int s = wave * 16 + lrow;
      #pragma unroll
      for (int ks = 0; ks < 2; ++ks) {
        short8 fa = zero8;
        if (s < SEQ_S) {
          const float* ap = ctx + ((size_t)b * SEQ_S + s) * DC + k0 + ks * 32 + quad * 8;
          fa = pack8(*(const float4*)ap, *(const float4*)(ap + 4));
        }
        short8 fb[5];
        #pragma unroll
        for (int j = 0; j < 5; ++j)
          fb[j] = *(const short8*)&Ws[(j * 16 + lrow) * 72 + ks * 32 + quad * 8];
        #pragma unroll
        for (int j = 0; j < 5; ++j)
          acc[j] = __builtin_amdgcn_mfma_f32_16x16x32_bf16(fa, fb[j], acc[j], 0, 0, 0);
      }
    }
  }
  if (wave < 5) {   // pack: n<40 -> K[s][n] (scale pre-folded); else Vt[n-40][s]
    #pragma unroll
    for (int j = 0; j < 5; ++j) {
      int n = j * 16 + lrow;
      #pragma unroll
      for (int r = 0; r < 4; ++r) {
        int s = wave * 16 + quad * 4 + r;
        if (s < SEQ_S) {
          unsigned short v = f2bf(acc[j][r]);
          if (n < DIM_HEAD) dst[s * 40 + n] = v;
          else              dst[3200 + (n - 40) * 104 + s] = v;
        }
      }
    }
  }
}

// --------------------------------------------------------------- fused kernel
// grid = 1024 (XCD-swizzled), 512 threads / 8 waves, LDS 40,960 B (qs only).
// Phase1/3: wave grid 2(m)x4(n), acc[2][5]. Phase2: wave -> 16 q-rows x 4 heads.
__global__ __launch_bounds__(512, 4) void fused_attn_kernel(
    const float* __restrict__ x, const unsigned short* __restrict__ WqT,
    const unsigned short* __restrict__ kvp, const unsigned short* __restrict__ WoT,
    const float* __restrict__ bo, float* __restrict__ out) {
  __shared__ __align__(16) unsigned short qs[64 * 320];   // 40,960 B
  const int tid = threadIdx.x;
  const int lane = tid & 63, wave = tid >> 6;
  const int lrow = lane & 15, quad = lane >> 4;
  const int bid = ((int)blockIdx.x & 7) * 128 + ((int)blockIdx.x >> 3);  // XCD swizzle
  const int b = bid >> 6;
  const int t0 = (bid & 63) * 64;
  const int wm = (wave & 1) * 32, wn = (wave >> 1) * 80;

  // ---- Phase 0: stage x tile -> bf16 qs (swizzled)
  {
    const float* xb = x + ((size_t)b * SEQ_T + t0) * DQ;
    const int row = tid >> 3, ub = tid & 7;
    const float* src0 = xb + (size_t)row * DQ;
    #pragma unroll
    for (int it = 0; it < 5; ++it) {
      int uc = ub + it * 8;
      float4 a  = *(const float4*)(src0 + uc * 8);
      float4 c2 = *(const float4*)(src0 + uc * 8 + 4);
      *(short8*)&qs[qsi(row, uc)] = pack8(a, c2);
    }
  }
  __syncthreads();

  // ---- Phase 1: q = x @ WqT (SCALE folded into WqT)
  {
    floatx4 acc[2][5];
    #pragma unroll
    for (int i = 0; i < 2; ++i)
      #pragma unroll
      for (int j = 0; j < 5; ++j) acc[i][j] = (floatx4){0.f, 0.f, 0.f, 0.f};

    auto ld = [&](int kb, short8 (&fb)[5], short8 (&fa)[2]) {
      #pragma unroll
      for (int j = 0; j < 5; ++j)
        fb[j] = *(const short8*)(WqT + (size_t)(wn + j * 16 + lrow) * 320 + kb * 32 + quad * 8);
      #pragma unroll
      for (int i = 0; i < 2; ++i) {
        int m = wm + i * 16 + lrow;
        fa[i] = *(const short8*)&qs[qsi(m, kb * 4 + quad)];
      }
    };
    auto mm = [&](short8 (&fa)[2], short8 (&fb)[5]) {
      #pragma unroll
      for (int i = 0; i < 2; ++i)
        #pragma unroll
        for (int j = 0; j < 5; ++j)
          acc[i][j] = __builtin_amdgcn_mfma_f32_16x16x32_bf16(fa[i], fb[j], acc[i][j], 0, 0, 0);
    };

    short8 fbA[5], fbB[5], faA[2], faB[2];
    ld(0, fbA, faA);
    #pragma unroll
    for (int t = 0; t < 5; ++t) {
      ld(2 * t + 1, fbB, faB);
      mm(faA, fbA);
      if (2 * t + 2 < 10) ld(2 * t + 2, fbA, faA);
      mm(faB, fbB);
    }
    __syncthreads();   // all waves done reading x from qs
    #pragma unroll
    for (int i = 0; i < 2; ++i)
      #pragma unroll
      for (int j = 0; j < 5; ++j)
        #pragma unroll
        for (int r = 0; r < 4; ++r) {
          int row = wm + i * 16 + quad * 4 + r, c = wn + j * 16 + lrow;
          qs[(row * 40 + ((c >> 3) ^ (row & 7))) * 8 + (c & 7)] = f2bf(acc[i][j][r]);
        }
  }
  __syncthreads();   // q visible to all waves

  // ---- Phase 2: attention (swapped QK^T, in-register softmax+redistribute).
  // Wave owns q rows [16*(wave&3), +16) for heads h = 2*t + (wave>>2).
  {
    const int W = (wave & 3) * 16;
    const int hp = wave >> 2;
    const int qrow = W + lrow;
    const short8 zero8 = {0, 0, 0, 0, 0, 0, 0, 0};
    const int sl_a0 = (quad & 1) * 32 + lrow;   // P redistribution src lanes
    const int sl_a1 = sl_a0 + 16;
    const bool jhi = quad >= 2;

    #pragma unroll 1
    for (int t = 0; t < 4; ++t) {
      const int h = 2 * t + hp;
      const unsigned short* kvt = kvp + (size_t)(b * NUM_HEADS + h) * 8192;
      // V fragments (issued early; consumed after softmax)
      short8 vb0[3], vb1[3], vb2[3];
      #pragma unroll
      for (int nj = 0; nj < 3; ++nj) {
        const unsigned short* vtb = kvt + 3200 + (size_t)(nj * 16 + lrow) * 104 + quad * 8;
        vb0[nj] = *(const short8*)(vtb);
        vb1[nj] = *(const short8*)(vtb + 32);
        vb2[nj] = *(const short8*)(vtb + 64);
      }
      // K fragments (A operand of swapped QK^T)
      short8 ka0[5], ka1[5];
      #pragma unroll
      for (int j = 0; j < 5; ++j) {
        const unsigned short* kbp = kvt + (size_t)(j * 16 + lrow) * 40;
        ka0[j] = *(const short8*)(kbp + quad * 8);
        ka1[j] = *(const short8*)(kbp + 32 + quad * 8);   // quads 1-3: finite x 0
      }
      short8 fq0 = *(const short8*)&qs[qsi(qrow, h * 5 + quad)];
      short8 fq1 = (quad == 0) ? *(const short8*)&qs[qsi(qrow, h * 5 + 4)] : zero8;

      floatx4 sc[5];
      #pragma unroll
      for (int j = 0; j < 5; ++j) sc[j] = (floatx4){0.f, 0.f, 0.f, 0.f};
      #pragma unroll
      for (int j = 0; j < 5; ++j) {
        sc[j] = __builtin_amdgcn_mfma_f32_16x16x32_bf16(ka0[j], fq0, sc[j], 0, 0, 0);
        sc[j] = __builtin_amdgcn_mfma_f32_16x16x32_bf16(ka1[j], fq1, sc[j], 0, 0, 0);
      }
      // sc[j][r] = P^T[s = j*16 + quad*4 + r][qrow]
      float p[5][4]; float csum = 0.f;
      #pragma unroll
      for (int j = 0; j < 5; ++j)
        #pragma unroll
        for (int r = 0; r < 4; ++r) {
          int s = j * 16 + quad * 4 + r;
          float v = (s < SEQ_S) ? __expf(sc[j][r]) : 0.f;
          p[j][r] = v; csum += v;
        }
      csum += __shfl_xor(csum, 16);
      csum += __shfl_xor(csum, 32);
      float inv = 1.0f / csum;        // per q-row

      unsigned pk0[5], pk1[5];
      #pragma unroll
      for (int j = 0; j < 5; ++j) {
        pk0[j] = (unsigned)f2bf(p[j][0]) | ((unsigned)f2bf(p[j][1]) << 16);
        pk1[j] = (unsigned)f2bf(p[j][2]) | ((unsigned)f2bf(p[j][3]) << 16);
      }
      // redistribute P^T -> PV A-fragments
      floatx4 oc[3];
      #pragma unroll
      for (int nj = 0; nj < 3; ++nj) oc[nj] = (floatx4){0.f, 0.f, 0.f, 0.f};
      #pragma unroll
      for (int ks = 0; ks < 3; ++ks) {
        unsigned wA0 = __shfl(pk0[2 * ks], sl_a0);
        unsigned wA1 = __shfl(pk1[2 * ks], sl_a0);
        unsigned wA2 = __shfl(pk0[2 * ks], sl_a1);
        unsigned wA3 = __shfl(pk1[2 * ks], sl_a1);
        unsigned wB0 = (2 * ks + 1 < 5) ? __shfl(pk0[2 * ks + 1], sl_a0) : 0u;
        unsigned wB1 = (2 * ks + 1 < 5) ? __shfl(pk1[2 * ks + 1], sl_a0) : 0u;
        unsigned wB2 = (2 * ks + 1 < 5) ? __shfl(pk0[2 * ks + 1], sl_a1) : 0u;
        unsigned wB3 = (2 * ks + 1 < 5) ? __shfl(pk1[2 * ks + 1], sl_a1) : 0u;
        union { unsigned u[4]; short8 s8; } pu;
        pu.u[0] = jhi ? wB0 : wA0;
        pu.u[1] = jhi ? wB1 : wA1;
        pu.u[2] = jhi ? wB2 : wA2;
        pu.u[3] = jhi ? wB3 : wA3;
        short8* vb = (ks == 0) ? vb0 : (ks == 1) ? vb1 : vb2;
        #pragma unroll
        for (int nj = 0; nj < 3; ++nj)
          oc[nj] = __builtin_amdgcn_mfma_f32_16x16x32_bf16(pu.s8, vb[nj], oc[nj], 0, 0, 0);
      }
      // normalize and write att into qs band [h*40, h*40+40)
      float invr[4];
      #pragma unroll
      for (int r = 0; r < 4; ++r) invr[r] = __shfl(inv, quad * 4 + r);
      #pragma unroll
      for (int nj = 0; nj < 3; ++nj) {
        int c = nj * 16 + lrow;
        if (c < DIM_HEAD) {
          #pragma unroll
          for (int r = 0; r < 4; ++r) {
            int row = W + quad * 4 + r, cc = h * 40 + c;
            qs[(row * 40 + ((cc >> 3) ^ (row & 7))) * 8 + (cc & 7)] =
                f2bf(oc[nj][r] * invr[r]);
          }
        }
      }
    }
  }
  __syncthreads();   // att ready for all waves

  // ---- Phase 3: out = att @ WoT + bo
  {
    floatx4 acc[2][5];
    #pragma unroll
    for (int i = 0; i < 2; ++i)
      #pragma unroll
      for (int j = 0; j < 5; ++j) acc[i][j] = (floatx4){0.f, 0.f, 0.f, 0.f};

    auto ld = [&](int kb, short8 (&fb)[5], short8 (&fa)[2]) {
      #pragma unroll
      for (int j = 0; j < 5; ++j)
        fb[j] = *(const short8*)(WoT + (size_t)(wn + j * 16 + lrow) * 320 + kb * 32 + quad * 8);
      #pragma unroll
      for (int i = 0; i < 2; ++i) {
        int m = wm + i * 16 + lrow;
        fa[i] = *(const short8*)&qs[qsi(m, kb * 4 + quad)];
      }
    };
    auto mm = [&](short8 (&fa)[2], short8 (&fb)[5]) {
      #pragma unroll
      for (int i = 0; i < 2; ++i)
        #pragma unroll
        for (int j = 0; j < 5; ++j)
          acc[i][j] = __builtin_amdgcn_mfma_f32_16x16x32_bf16(fa[i], fb[j], acc[i][j], 0, 0, 0);
    };

    short8 fbA[5], fbB[5], faA[2], faB[2];
    ld(0, fbA, faA);
    #pragma unroll
    for (int t = 0; t < 5; ++t) {
      ld(2 * t + 1, fbB, faB);
      mm(faA, fbA);
      if (2 * t + 2 < 10) ld(2 * t + 2, fbA, faA);
      mm(faB, fbB);
    }
    float* ob = out + ((size_t)b * SEQ_T + t0) * DQ;
    #pragma unroll
    for (int i = 0; i < 2; ++i)
      #pragma unroll
      for (int j = 0; j < 5; ++j) {
        int n = wn + j * 16 + lrow;
        float bv = bo[n];
        #pragma unroll
        for (int r = 0; r < 4; ++r)
          ob[(size_t)(wm + i * 16 + quad * 4 + r) * DQ + n] = acc[i][j][r] + bv;
      }
  }
}

// -------------------------------------------------------------------- launch
extern "C" void kernel_launch(void* const* d_in, const int* in_sizes, int n_in,
                              void* d_out, int out_size, void* d_ws, size_t ws_size,
                              hipStream_t stream) {
  const float* x   = (const float*)d_in[0];
  const float* ctx = (const float*)d_in[1];
  const float* Wq  = (const float*)d_in[2];
  const float* Wk  = (const float*)d_in[3];
  const float* Wv  = (const float*)d_in[4];
  const float* Wo  = (const float*)d_in[5];
  const float* bo  = (const float*)d_in[6];
  float* out = (float*)d_out;

  char* w = (char*)d_ws;
  unsigned short* WqT = (unsigned short*)(w);             //   204,800 B
  unsigned short* WoT = (unsigned short*)(w + 204800);    //   204,800 B
  unsigned short* kvp = (unsigned short*)(w + 409600);    // 2,097,152 B -> 2,506,752

  hipLaunchKernelGGL(prep_kernel, dim3(328), dim3(512), 0, stream,
                     ctx, Wq, Wk, Wv, Wo, WqT, WoT, kvp);
  hipLaunchKernelGGL(fused_attn_kernel, dim3(1024), dim3(512), 0, stream,
                     x, WqT, kvp, WoT, bo, out);
}

// Round 6
// 225.175 us; speedup vs baseline: 1.3625x; 1.3625x over previous
//
#include <hip/hip_runtime.h>
#include <math.h>

// Round 11: fragment-packed operands. r9/r10's strided 16B/lane fragment loads
// (row stride 640B) touched 16 cachelines per 1KB useful -> ~4x L2 traffic
// amplification x 1024 blocks ~= 5-6 GB ~= 170us at L2 aggregate BW -- the
// invariant that pinned rounds 8-10 at ~165us. Fix: pre-pack Wq/Wo/K/V into
// MFMA-fragment-contiguous layout (1KB fully-coalesced load per fragment,
// L1-hot across waves). launch_bounds(512,2) kills r10's VGPR-64 spills.
// prep split into prep_w (transpose+pack) + prep_kv (fragment GEMM, 0 barriers).

#define NUM_HEADS 8
#define DIM_HEAD 40
#define INNER 320
#define DQ 320
#define DC 768
#define SEQ_T 4096
#define SEQ_S 77
#define BATCH 16
#define SCALE 0.39763536438352531f

typedef __attribute__((ext_vector_type(8))) short short8;
typedef __attribute__((ext_vector_type(4))) float floatx4;

__device__ __forceinline__ unsigned short f2bf(float f) {
  unsigned u = __float_as_uint(f);
  u += 0x7FFFu + ((u >> 16) & 1u);   // RNE
  return (unsigned short)(u >> 16);
}

__device__ __forceinline__ short8 pack8(float4 a, float4 b) {
  short8 pk;
  pk[0] = (short)f2bf(a.x); pk[1] = (short)f2bf(a.y);
  pk[2] = (short)f2bf(a.z); pk[3] = (short)f2bf(a.w);
  pk[4] = (short)f2bf(b.x); pk[5] = (short)f2bf(b.y);
  pk[6] = (short)f2bf(b.z); pk[7] = (short)f2bf(b.w);
  return pk;
}

// qs swizzle: 16B-unit index for (row, unit-col). 40 units per 320-short row.
__device__ __forceinline__ int qsi(int row, int uc) {
  return (row * 40 + (uc ^ (row & 7))) * 8;
}

// ------------------------------------------------- prep_w: transpose + pack
// Fragment layout: frag(kb,jt) holds W^T[n=jt*16+(l&15)][k=kb*32+(l>>4)*8+e]
// at [((kb*NT + jt)*64 + l)*8 + e].  Wq/Wo: NT=20, 10 kb. Wk/Wv -> Wkvp per
// head h: NT=5 (c 0..79 = K|V), 24 kb, base h*61440 shorts.
// grid 680 x 256: [0,100) Wq | [100,200) Wo | [200,440) Wk | [440,680) Wv.
__global__ __launch_bounds__(256) void prep_w_kernel(
    const float* __restrict__ Wq, const float* __restrict__ Wo,
    const float* __restrict__ Wk, const float* __restrict__ Wv,
    unsigned short* __restrict__ Wqp, unsigned short* __restrict__ Wop,
    unsigned short* __restrict__ Wkvp) {
  __shared__ float tile[32][33];
  const int bid = blockIdx.x, tid = threadIdx.x;
  const float* W; float scl; int mode, kt, nt;
  if (bid < 100)      { W = Wq; scl = SCALE; mode = 0; kt = bid % 10; nt = bid / 10; }
  else if (bid < 200) { W = Wo; scl = 1.f;   mode = 1; int z = bid - 100; kt = z % 10; nt = z / 10; }
  else if (bid < 440) { W = Wk; scl = SCALE; mode = 2; int z = bid - 200; kt = z % 24; nt = z / 24; }
  else                { W = Wv; scl = 1.f;   mode = 3; int z = bid - 440; kt = z % 24; nt = z / 24; }
  const int k0 = kt * 32, n0 = nt * 32;
  const int tx = tid & 31, ty = tid >> 5;
  #pragma unroll
  for (int r = 0; r < 4; ++r)
    tile[ty + r * 8][tx] = W[(size_t)(k0 + ty + r * 8) * 320 + n0 + tx];
  __syncthreads();
  const int k = k0 + tx, e = k & 7, lq = (k >> 3) & 3;
  #pragma unroll
  for (int r = 0; r < 4; ++r) {
    int n = n0 + ty + r * 8;
    unsigned short v = f2bf(tile[tx][ty + r * 8] * scl);
    if (mode < 2) {
      unsigned short* Wp = (mode == 0) ? Wqp : Wop;
      int jt = n >> 4;
      Wp[(((size_t)kt * 20 + jt) * 64 + lq * 16 + (n & 15)) * 8 + e] = v;
    } else {
      int h = n / 40, c = n - h * 40 + (mode == 3 ? 40 : 0);
      int jt = c >> 4;
      Wkvp[((((size_t)h * 24 + kt) * 5 + jt) * 64 + lq * 16 + (c & 15)) * 8 + e] = v;
    }
  }
}

// ------------------------------------------------- prep_kv: fragment GEMM
// grid 128 (b,h) x 512. Zero-fill tile (pad addrs disjoint from pack addrs ->
// no ordering needed), waves 5-7 exit, waves 0-4 compute K|V = ctx @ W' via
// coalesced fragment loads (no LDS, no barriers) and pack to kvp fragments:
// Kmain[5 frag]@0 | Ktail[5 frag]@2560 | V[9 frag]@5120, tile = 10240 shorts.
__global__ __launch_bounds__(512) void prep_kv_kernel(
    const float* __restrict__ ctx, const unsigned short* __restrict__ Wkvp,
    unsigned short* __restrict__ kvp) {
  const int bid = blockIdx.x, tid = threadIdx.x;
  const int b = bid >> 3, h = bid & 7;
  unsigned short* dst = kvp + (size_t)bid * 10240;
  {
    int4 zv = make_int4(0, 0, 0, 0);
    for (int i = tid; i < 1280; i += 512) ((int4*)dst)[i] = zv;
  }
  const int lane = tid & 63, wave = tid >> 6;
  if (wave >= 5) return;
  const int lrow = lane & 15, quad = lane >> 4;
  const int s_ld = wave * 16 + lrow;
  const bool sv = s_ld < SEQ_S;
  const float* arow = ctx + ((size_t)b * SEQ_S + s_ld) * DC;
  const unsigned short* wb = Wkvp + (size_t)h * 61440;
  const short8 zero8 = {0, 0, 0, 0, 0, 0, 0, 0};

  floatx4 acc[5];
  #pragma unroll
  for (int j = 0; j < 5; ++j) acc[j] = (floatx4){0.f, 0.f, 0.f, 0.f};

  auto ld = [&](int kc, short8& fa, short8 (&fb)[5]) {
    fa = zero8;
    if (sv) {
      const float* ap = arow + kc * 32 + quad * 8;
      fa = pack8(*(const float4*)ap, *(const float4*)(ap + 4));
    }
    #pragma unroll
    for (int j = 0; j < 5; ++j)
      fb[j] = *(const short8*)(wb + (((size_t)kc * 5 + j) * 64 + lane) * 8);
  };
  auto mm = [&](short8& fa, short8 (&fb)[5]) {
    #pragma unroll
    for (int j = 0; j < 5; ++j)
      acc[j] = __builtin_amdgcn_mfma_f32_16x16x32_bf16(fa, fb[j], acc[j], 0, 0, 0);
  };

  short8 faA, faB, fbA[5], fbB[5];
  ld(0, faA, fbA);
  #pragma unroll
  for (int t = 0; t < 12; ++t) {
    ld(2 * t + 1, faB, fbB);
    mm(faA, fbA);
    if (2 * t + 2 < 24) ld(2 * t + 2, faA, fbA);
    mm(faB, fbB);
  }

  // pack epilogue: D element (s = wave*16+quad*4+r, col n_c = j*16+lrow)
  #pragma unroll
  for (int j = 0; j < 5; ++j) {
    int n_c = j * 16 + lrow;
    #pragma unroll
    for (int r = 0; r < 4; ++r) {
      int s = wave * 16 + quad * 4 + r;
      if (s < SEQ_S) {
        unsigned short v = f2bf(acc[j][r]);
        if (n_c < DIM_HEAD) {   // K[s][c]
          int c = n_c;
          if (c < 32)
            dst[(((size_t)(s >> 4)) * 64 + (c >> 3) * 16 + (s & 15)) * 8 + (c & 7)];
          if (c < 32)
            dst[(((size_t)(s >> 4)) * 64 + (c >> 3) * 16 + (s & 15)) * 8 + (c & 7)] = v;
          else
            dst[2560 + (((size_t)(s >> 4)) * 64 + (s & 15)) * 8 + (c - 32)] = v;
        } else {                // V[s][c]
          int c = n_c - DIM_HEAD;
          int lane2 = ((s & 31) >> 3) * 16 + (c & 15);
          dst[5120 + (((size_t)((c >> 4) * 3 + (s >> 5))) * 64 + lane2) * 8 + (s & 7)] = v;
        }
      }
    }
  }
}

// --------------------------------------------------------------- fused kernel
// grid 1024 (XCD-swizzled), 512 thr / 8 waves, LDS 40,960 B (qs only).
// All B-operand fragment loads are packed-contiguous (1KB/instr, L1-hot).
__global__ __launch_bounds__(512, 2) void fused_attn_kernel(
    const float* __restrict__ x, const unsigned short* __restrict__ Wqp,
    const unsigned short* __restrict__ kvp, const unsigned short* __restrict__ Wop,
    const float* __restrict__ bo, float* __restrict__ out) {
  __shared__ __align__(16) unsigned short qs[64 * 320];   // 40,960 B
  const int tid = threadIdx.x;
  const int lane = tid & 63, wave = tid >> 6;
  const int lrow = lane & 15, quad = lane >> 4;
  const int bid = ((int)blockIdx.x & 7) * 128 + ((int)blockIdx.x >> 3);  // XCD swizzle
  const int b = bid >> 6;
  const int t0 = (bid & 63) * 64;
  const int wm = (wave & 1) * 32, wn = (wave >> 1) * 80;
  const int jtb = (wave >> 1) * 5;

  // ---- Phase 0: stage x tile -> bf16 qs (swizzled)
  {
    const float* xb = x + ((size_t)b * SEQ_T + t0) * DQ;
    const int row = tid >> 3, ub = tid & 7;
    const float* src0 = xb + (size_t)row * DQ;
    #pragma unroll
    for (int it = 0; it < 5; ++it) {
      int uc = ub + it * 8;
      float4 a  = *(const float4*)(src0 + uc * 8);
      float4 c2 = *(const float4*)(src0 + uc * 8 + 4);
      *(short8*)&qs[qsi(row, uc)] = pack8(a, c2);
    }
  }
  __syncthreads();

  // ---- Phase 1: q = x @ Wq^T (SCALE folded), packed fb loads
  {
    floatx4 acc[2][5];
    #pragma unroll
    for (int i = 0; i < 2; ++i)
      #pragma unroll
      for (int j = 0; j < 5; ++j) acc[i][j] = (floatx4){0.f, 0.f, 0.f, 0.f};

    auto ld = [&](int kb, short8 (&fb)[5], short8 (&fa)[2]) {
      #pragma unroll
      for (int j = 0; j < 5; ++j)
        fb[j] = *(const short8*)(Wqp + (((size_t)kb * 20 + jtb + j) * 64 + lane) * 8);
      #pragma unroll
      for (int i = 0; i < 2; ++i) {
        int m = wm + i * 16 + lrow;
        fa[i] = *(const short8*)&qs[qsi(m, kb * 4 + quad)];
      }
    };
    auto mm = [&](short8 (&fa)[2], short8 (&fb)[5]) {
      #pragma unroll
      for (int i = 0; i < 2; ++i)
        #pragma unroll
        for (int j = 0; j < 5; ++j)
          acc[i][j] = __builtin_amdgcn_mfma_f32_16x16x32_bf16(fa[i], fb[j], acc[i][j], 0, 0, 0);
    };

    short8 fbA[5], fbB[5], faA[2], faB[2];
    ld(0, fbA, faA);
    #pragma unroll
    for (int t = 0; t < 5; ++t) {
      ld(2 * t + 1, fbB, faB);
      mm(faA, fbA);
      if (2 * t + 2 < 10) ld(2 * t + 2, fbA, faA);
      mm(faB, fbB);
    }
    __syncthreads();   // all waves done reading x from qs
    #pragma unroll
    for (int i = 0; i < 2; ++i)
      #pragma unroll
      for (int j = 0; j < 5; ++j)
        #pragma unroll
        for (int r = 0; r < 4; ++r) {
          int row = wm + i * 16 + quad * 4 + r, c = wn + j * 16 + lrow;
          qs[(row * 40 + ((c >> 3) ^ (row & 7))) * 8 + (c & 7)] = f2bf(acc[i][j][r]);
        }
  }
  __syncthreads();   // q visible to all waves

  // ---- Phase 2: attention (swapped QK^T, in-register softmax+redistribute).
  // Wave owns q rows [16*(wave&3), +16) for heads h = 2*t + (wave>>2).
  {
    const int W = (wave & 3) * 16;
    const int hp = wave >> 2;
    const int qrow = W + lrow;
    const short8 zero8 = {0, 0, 0, 0, 0, 0, 0, 0};
    const int sl_a0 = (quad & 1) * 32 + lrow;   // P redistribution src lanes
    const int sl_a1 = sl_a0 + 16;
    const bool jhi = quad >= 2;

    #pragma unroll 1
    for (int t = 0; t < 4; ++t) {
      const int h = 2 * t + hp;
      const unsigned short* kvt = kvp + (size_t)(b * NUM_HEADS + h) * 10240;
      // K fragments (packed; Ktail pad lanes are real zeros)
      short8 ka0[5], ka1[5];
      #pragma unroll
      for (int j = 0; j < 5; ++j) {
        ka0[j] = *(const short8*)(kvt + ((size_t)j * 64 + lane) * 8);
        ka1[j] = *(const short8*)(kvt + 2560 + ((size_t)j * 64 + lane) * 8);
      }
      short8 fq0 = *(const short8*)&qs[qsi(qrow, h * 5 + quad)];
      short8 fq1 = (quad == 0) ? *(const short8*)&qs[qsi(qrow, h * 5 + 4)] : zero8;

      floatx4 sc[5];
      #pragma unroll
      for (int j = 0; j < 5; ++j) sc[j] = (floatx4){0.f, 0.f, 0.f, 0.f};
      #pragma unroll
      for (int j = 0; j < 5; ++j) {
        sc[j] = __builtin_amdgcn_mfma_f32_16x16x32_bf16(ka0[j], fq0, sc[j], 0, 0, 0);
        sc[j] = __builtin_amdgcn_mfma_f32_16x16x32_bf16(ka1[j], fq1, sc[j], 0, 0, 0);
      }
      // sc[j][r] = P^T[s = j*16 + quad*4 + r][qrow]
      float p[5][4]; float csum = 0.f;
      #pragma unroll
      for (int j = 0; j < 5; ++j)
        #pragma unroll
        for (int r = 0; r < 4; ++r) {
          int s = j * 16 + quad * 4 + r;
          float v = (s < SEQ_S) ? __expf(sc[j][r]) : 0.f;
          p[j][r] = v; csum += v;
        }
      csum += __shfl_xor(csum, 16);
      csum += __shfl_xor(csum, 32);
      float inv = 1.0f / csum;        // per q-row

      unsigned pk0[5], pk1[5];
      #pragma unroll
      for (int j = 0; j < 5; ++j) {
        pk0[j] = (unsigned)f2bf(p[j][0]) | ((unsigned)f2bf(p[j][1]) << 16);
        pk1[j] = (unsigned)f2bf(p[j][2]) | ((unsigned)f2bf(p[j][3]) << 16);
      }
      // V fragments (packed, loaded after softmax to cap VGPR peak)
      short8 vb0[3], vb1[3], vb2[3];
      #pragma unroll
      for (int nj = 0; nj < 3; ++nj) {
        vb0[nj] = *(const short8*)(kvt + 5120 + (((size_t)nj * 3 + 0) * 64 + lane) * 8);
        vb1[nj] = *(const short8*)(kvt + 5120 + (((size_t)nj * 3 + 1) * 64 + lane) * 8);
        vb2[nj] = *(const short8*)(kvt + 5120 + (((size_t)nj * 3 + 2) * 64 + lane) * 8);
      }
      // redistribute P^T -> PV A-fragments
      floatx4 oc[3];
      #pragma unroll
      for (int nj = 0; nj < 3; ++nj) oc[nj] = (floatx4){0.f, 0.f, 0.f, 0.f};
      #pragma unroll
      for (int ks = 0; ks < 3; ++ks) {
        unsigned wA0 = __shfl(pk0[2 * ks], sl_a0);
        unsigned wA1 = __shfl(pk1[2 * ks], sl_a0);
        unsigned wA2 = __shfl(pk0[2 * ks], sl_a1);
        unsigned wA3 = __shfl(pk1[2 * ks], sl_a1);
        unsigned wB0 = (2 * ks + 1 < 5) ? __shfl(pk0[2 * ks + 1], sl_a0) : 0u;
        unsigned wB1 = (2 * ks + 1 < 5) ? __shfl(pk1[2 * ks + 1], sl_a0) : 0u;
        unsigned wB2 = (2 * ks + 1 < 5) ? __shfl(pk0[2 * ks + 1], sl_a1) : 0u;
        unsigned wB3 = (2 * ks + 1 < 5) ? __shfl(pk1[2 * ks + 1], sl_a1) : 0u;
        union { unsigned u[4]; short8 s8; } pu;
        pu.u[0] = jhi ? wB0 : wA0;
        pu.u[1] = jhi ? wB1 : wA1;
        pu.u[2] = jhi ? wB2 : wA2;
        pu.u[3] = jhi ? wB3 : wA3;
        short8* vb = (ks == 0) ? vb0 : (ks == 1) ? vb1 : vb2;
        #pragma unroll
        for (int nj = 0; nj < 3; ++nj)
          oc[nj] = __builtin_amdgcn_mfma_f32_16x16x32_bf16(pu.s8, vb[nj], oc[nj], 0, 0, 0);
      }
      // normalize and write att into qs band [h*40, h*40+40)
      float invr[4];
      #pragma unroll
      for (int r = 0; r < 4; ++r) invr[r] = __shfl(inv, quad * 4 + r);
      #pragma unroll
      for (int nj = 0; nj < 3; ++nj) {
        int c = nj * 16 + lrow;
        if (c < DIM_HEAD) {
          #pragma unroll
          for (int r = 0; r < 4; ++r) {
            int row = W + quad * 4 + r, cc = h * 40 + c;
            qs[(row * 40 + ((cc >> 3) ^ (row & 7))) * 8 + (cc & 7)] =
                f2bf(oc[nj][r] * invr[r]);
          }
        }
      }
    }
  }
  __syncthreads();   // att ready for all waves

  // ---- Phase 3: out = att @ Wo^T + bo, packed fb loads
  {
    floatx4 acc[2][5];
    #pragma unroll
    for (int i = 0; i < 2; ++i)
      #pragma unroll
      for (int j = 0; j < 5; ++j) acc[i][j] = (floatx4){0.f, 0.f, 0.f, 0.f};

    auto ld = [&](int kb, short8 (&fb)[5], short8 (&fa)[2]) {
      #pragma unroll
      for (int j = 0; j < 5; ++j)
        fb[j] = *(const short8*)(Wop + (((size_t)kb * 20 + jtb + j) * 64 + lane) * 8);
      #pragma unroll
      for (int i = 0; i < 2; ++i) {
        int m = wm + i * 16 + lrow;
        fa[i] = *(const short8*)&qs[qsi(m, kb * 4 + quad)];
      }
    };
    auto mm = [&](short8 (&fa)[2], short8 (&fb)[5]) {
      #pragma unroll
      for (int i = 0; i < 2; ++i)
        #pragma unroll
        for (int j = 0; j < 5; ++j)
          acc[i][j] = __builtin_amdgcn_mfma_f32_16x16x32_bf16(fa[i], fb[j], acc[i][j], 0, 0, 0);
    };

    short8 fbA[5], fbB[5], faA[2], faB[2];
    ld(0, fbA, faA);
    #pragma unroll
    for (int t = 0; t < 5; ++t) {
      ld(2 * t + 1, fbB, faB);
      mm(faA, fbA);
      if (2 * t + 2 < 10) ld(2 * t + 2, fbA, faA);
      mm(faB, fbB);
    }
    float* ob = out + ((size_t)b * SEQ_T + t0) * DQ;
    #pragma unroll
    for (int i = 0; i < 2; ++i)
      #pragma unroll
      for (int j = 0; j < 5; ++j) {
        int n = wn + j * 16 + lrow;
        float bv = bo[n];
        #pragma unroll
        for (int r = 0; r < 4; ++r)
          ob[(size_t)(wm + i * 16 + quad * 4 + r) * DQ + n] = acc[i][j][r] + bv;
      }
  }
}

// -------------------------------------------------------------------- launch
extern "C" void kernel_launch(void* const* d_in, const int* in_sizes, int n_in,
                              void* d_out, int out_size, void* d_ws, size_t ws_size,
                              hipStream_t stream) {
  const float* x   = (const float*)d_in[0];
  const float* ctx = (const float*)d_in[1];
  const float* Wq  = (const float*)d_in[2];
  const float* Wk  = (const float*)d_in[3];
  const float* Wv  = (const float*)d_in[4];
  const float* Wo  = (const float*)d_in[5];
  const float* bo  = (const float*)d_in[6];
  float* out = (float*)d_out;

  char* w = (char*)d_ws;
  unsigned short* Wqp  = (unsigned short*)(w);             //   204,800 B
  unsigned short* Wop  = (unsigned short*)(w + 204800);    //   204,800 B
  unsigned short* Wkvp = (unsigned short*)(w + 409600);    //   983,040 B
  unsigned short* kvp  = (unsigned short*)(w + 1392640);   // 2,621,440 B -> 4,014,080

  hipLaunchKernelGGL(prep_w_kernel, dim3(680), dim3(256), 0, stream,
                     Wq, Wo, Wk, Wv, Wqp, Wop, Wkvp);
  hipLaunchKernelGGL(prep_kv_kernel, dim3(128), dim3(512), 0, stream,
                     ctx, Wkvp, kvp);
  hipLaunchKernelGGL(fused_attn_kernel, dim3(1024), dim3(512), 0, stream,
                     x, Wqp, kvp, Wop, bo, out);
}